// Round 3
// baseline (81.070 us; speedup 1.0000x reference)
//
#include <hip/hip_runtime.h>

// Biquad IIR scan, B=256 batches, T=65536 steps, 3 feedforward taps.
// y[n] = c0*x0 + c1*x1 + c2*x2 + a1*y[n-1] + a2*y[n-2]
// Poles at radius 0.5 => state contribution decays 0.5^k; a W-step warm-up
// from zero state makes time-chunks independent to ~2e-10 (threshold 3.7e-2).

constexpr int B_ = 256;
constexpr int T_ = 65536;
constexpr int C_ = 256;          // chunk length per thread
constexpr int W_ = 32;           // warm-up steps (error ~ 0.5^32 ~ 2e-10)
constexpr int NCHUNK = T_ / C_;  // 256 chunks per batch

__global__ __launch_bounds__(256) void biquad_kernel(
    const float* __restrict__ x,      // [B, T, 3]
    const float* __restrict__ carry0, // [B, 2] = (y[-1], y[-2])
    const float* __restrict__ coef,   // [5] = b0,b1,b2,-a1,-a2
    float* __restrict__ y)            // [B, T]
{
    const int tid   = blockIdx.x * blockDim.x + threadIdx.x;
    const int b     = tid / NCHUNK;
    const int chunk = tid - b * NCHUNK;
    const int t0    = chunk * C_;

    // coef pointer + indices are wave-uniform -> scalar loads
    const float c0 = coef[0], c1 = coef[1], c2 = coef[2];
    const float a1 = coef[3], a2 = coef[4];

    float y1, y2;  // y[n-1], y[n-2]
    if (chunk == 0) {
        y1 = carry0[2 * b + 0];
        y2 = carry0[2 * b + 1];
    } else {
        // Warm-up: W_ steps starting from zero state. (t0-W_)*12 bytes is
        // 16B-aligned (t0 mult of 256, W_ mult of 4), so float4 loads are legal.
        y1 = 0.0f; y2 = 0.0f;
        const float4* xw =
            (const float4*)(x + ((size_t)b * T_ + (size_t)(t0 - W_)) * 3);
        #pragma unroll
        for (int i = 0; i < W_ / 4; ++i) {
            float4 v0 = xw[3 * i + 0];
            float4 v1 = xw[3 * i + 1];
            float4 v2 = xw[3 * i + 2];
            float o0 = c0 * v0.x + c1 * v0.y + c2 * v0.z + a1 * y1 + a2 * y2;
            float o1 = c0 * v0.w + c1 * v1.x + c2 * v1.y + a1 * o0 + a2 * y1;
            float o2 = c0 * v1.z + c1 * v1.w + c2 * v2.x + a1 * o1 + a2 * o0;
            float o3 = c0 * v2.y + c1 * v2.z + c2 * v2.w + a1 * o2 + a2 * o1;
            y2 = o2; y1 = o3;
        }
    }

    // Main chunk: 4 steps per iteration = 3 float4 loads + 1 float4 store.
    const float4* xp = (const float4*)(x + ((size_t)b * T_ + (size_t)t0) * 3);
    float4* yp = (float4*)(y + (size_t)b * T_ + (size_t)t0);

    constexpr int ITERS = C_ / 4;
    float4 n0 = xp[0], n1 = xp[1], n2 = xp[2];  // register prefetch
    #pragma unroll 4
    for (int i = 0; i < ITERS; ++i) {
        const float4 v0 = n0, v1 = n1, v2 = n2;
        if (i + 1 < ITERS) {  // prefetch next 4 steps (keeps loads in flight)
            n0 = xp[3 * i + 3];
            n1 = xp[3 * i + 4];
            n2 = xp[3 * i + 5];
        }
        float o0 = c0 * v0.x + c1 * v0.y + c2 * v0.z + a1 * y1 + a2 * y2;
        float o1 = c0 * v0.w + c1 * v1.x + c2 * v1.y + a1 * o0 + a2 * y1;
        float o2 = c0 * v1.z + c1 * v1.w + c2 * v2.x + a1 * o1 + a2 * o0;
        float o3 = c0 * v2.y + c1 * v2.z + c2 * v2.w + a1 * o2 + a2 * o1;
        y2 = o2; y1 = o3;
        yp[i] = make_float4(o0, o1, o2, o3);
    }
}

extern "C" void kernel_launch(void* const* d_in, const int* in_sizes, int n_in,
                              void* d_out, int out_size, void* d_ws, size_t ws_size,
                              hipStream_t stream) {
    const float* x      = (const float*)d_in[0];  // [B,T,3] fp32
    const float* carry0 = (const float*)d_in[1];  // [B,2]
    const float* coef   = (const float*)d_in[2];  // [5]
    float* y = (float*)d_out;                     // [B,T,1] fp32

    const int total_threads = B_ * NCHUNK;        // 65536
    dim3 block(256);
    dim3 grid(total_threads / 256);               // 256 blocks
    biquad_kernel<<<grid, block, 0, stream>>>(x, carry0, coef, y);
}